// Round 15
// baseline (591.547 us; speedup 1.0000x reference)
//
#include <hip/hip_runtime.h>

// Geo-FFNO forward: factored Fourier (DFT -> per-mode complex mix -> iDFT, 16 modes)
// + FFN (Linear 128->512, ReLU, Linear 512->128, +bias, LayerNorm).
// B=16, M=N=128, D=I=O=128, NM=16, H=512.  FFN row count M_total = 16*128*128 = 262144.
//
// R15: R12's k_fft was still latency-bound (~180 VGPR, grid 512 blocks = 1 wave/SIMD;
// stride-64KB x loads exposed). Mode-split x4: each block does 4 modes x 4 rows
// (acc 32 VGPR, grid 2048 = 4 waves/SIMD). x re-reads hit L3. Everything else
// identical to R14 (passed).

#define LN_EPS 1e-5f
#define NMODES 16
#define FROW 4096     // per-row F/f size: 16k * 2 * 128
#define HROW 16384    // per (b,m) h row: 128*128

typedef __attribute__((ext_vector_type(8))) short short8;
typedef __attribute__((ext_vector_type(8))) ushort ushort8;
typedef __attribute__((ext_vector_type(4))) ushort ushort4v;
typedef __attribute__((ext_vector_type(4))) short short4v;
typedef __attribute__((ext_vector_type(4))) float f32x4;

__device__ __forceinline__ ushort f2bf(float f) {
    unsigned u = __float_as_uint(f);
    unsigned r = (u + 0x7FFFu + ((u >> 16) & 1u)) >> 16;   // RNE
    return (ushort)r;
}
__device__ __forceinline__ float bf2f(ushort h) {
    return __uint_as_float(((unsigned)h) << 16);
}

// ---------------- tables ----------------
__global__ void k_setup(float* __restrict__ Tc, float* __restrict__ Ts,
                        float* __restrict__ IT) {
    const float invs = 0.08838834764831845f;  // 1/sqrt(128)
    for (int idx = threadIdx.x; idx < NMODES * 128; idx += blockDim.x) {
        int k = idx >> 7, n = idx & 127;
        int p = (k * n) & 127;                 // periodic reduction
        float th = (float)p * (6.283185307179586f / 128.0f);
        float c = cosf(th), s = sinf(th);
        Tc[idx] = c * invs;                    // forward: (1/sqrtN) cos
        Ts[idx] = -s * invs;                   // forward: -(1/sqrtN) sin
        float ck = (k == 0) ? invs : 2.0f * invs;
        IT[n * 32 + 2 * k]     = ck * c;       // inverse: c_k cos
        IT[n * 32 + 2 * k + 1] = -ck * s;      // inverse: -c_k sin
    }
}

// ---------------- packed complex-mix weights, transposed, bf16 hi/lo ----------------
// Layout: [k][op][ip]; value(ip,op): ip<128: (op<128? re : im); ip>=128: (op<128? -im : re)
__global__ void k_wpack(const float* __restrict__ w, ushort* __restrict__ Wph,
                        ushort* __restrict__ Wpl) {
    int idx = blockIdx.x * 256 + threadIdx.x;  // 16*256*256 = 1,048,576
    int k  = idx >> 16;
    int op = (idx >> 8) & 255;
    int ip = idx & 255;
    int i = ip & 127, o = op & 127;
    const float* base = w + (((i << 7) | o) * NMODES + k) * 2;
    float re = base[0], im = base[1];
    float v = (ip < 128) ? ((op < 128) ? re : im)
                         : ((op < 128) ? -im : re);
    ushort hi = f2bf(v);
    ushort lo = f2bf(v - bf2f(hi));
    Wph[idx] = hi;
    Wpl[idx] = lo;
}

// ---------------- bf16 FFN weights (once) ----------------
// w0t[h][k] = w0[k][h]  (512x128 bf16); w1t[o][h] = w1[h][o]  (128x512 bf16)
__global__ __launch_bounds__(256) void k_wcvt(const float* __restrict__ w0,
        const float* __restrict__ w1, ushort* __restrict__ w0t,
        ushort* __restrict__ w1t) {
    int idx = blockIdx.x * 256 + threadIdx.x;   // 65536
    int h = idx >> 7, k = idx & 127;
    w0t[idx] = f2bf(w0[k * 512 + h]);
    int o = idx >> 9, hh = idx & 511;
    w1t[idx] = f2bf(w1[hh * 128 + o]);
}

// ---------------- truncated forward DFT (mode-split x4) ----------------
// Block 128 thr = 4 rows x 32 channel-groups (4 ch each). blockIdx&3 selects a
// 4-mode group. Grid 2048. acc = re/im[4] f32x4 (~95 VGPR -> 4 waves/SIMD).
__global__ __launch_bounds__(128) void k_fft(const float* __restrict__ x,
        const float* __restrict__ Tc, const float* __restrict__ Ts,
        float* __restrict__ F, int mode) {
    __shared__ float Tc_s[4 * 128];
    __shared__ float Ts_s[4 * 128];
    int mh = blockIdx.x & 3;
    int k0 = mh * 4;
    for (int e = threadIdx.x; e < 4 * 128; e += 128) {
        Tc_s[e] = Tc[k0 * 128 + e];
        Ts_s[e] = Ts[k0 * 128 + e];
    }
    __syncthreads();
    int row = (blockIdx.x >> 2) * 4 + (threadIdx.x >> 5);
    int i0 = (threadIdx.x & 31) * 4;
    size_t base; int ts;
    if (mode == 0) { base = (size_t)row * HROW; ts = 128; }
    else { base = (size_t)(row >> 7) * 2097152 + (size_t)(row & 127) * 128; ts = 16384; }

    f32x4 re[4], im[4];
#pragma unroll
    for (int k = 0; k < 4; ++k) {
        re[k] = {0.f, 0.f, 0.f, 0.f};
        im[k] = {0.f, 0.f, 0.f, 0.f};
    }

    f32x4 xv[4];
#pragma unroll
    for (int j = 0; j < 4; ++j)
        xv[j] = *(const f32x4*)(x + base + (size_t)j * ts + i0);

#pragma unroll 1
    for (int tb = 0; tb < 32; ++tb) {
        int t0 = tb * 4;
        f32x4 nx[4];
        if (tb < 31) {
#pragma unroll
            for (int j = 0; j < 4; ++j)
                nx[j] = *(const f32x4*)(x + base + (size_t)(t0 + 4 + j) * ts + i0);
        }
#pragma unroll
        for (int k = 0; k < 4; ++k) {
            f32x4 c4 = *(const f32x4*)&Tc_s[k * 128 + t0];
            f32x4 s4 = *(const f32x4*)&Ts_s[k * 128 + t0];
#pragma unroll
            for (int q = 0; q < 4; ++q) {
                re[k][q] += xv[0][q] * c4[0] + xv[1][q] * c4[1]
                          + xv[2][q] * c4[2] + xv[3][q] * c4[3];
                im[k][q] += xv[0][q] * s4[0] + xv[1][q] * s4[1]
                          + xv[2][q] * s4[2] + xv[3][q] * s4[3];
            }
        }
        if (tb < 31) {
#pragma unroll
            for (int j = 0; j < 4; ++j) xv[j] = nx[j];
        }
    }
    float* outp = F + (size_t)row * FROW;
#pragma unroll
    for (int k = 0; k < 4; ++k) {
        *(f32x4*)(outp + (k0 + k) * 256 + i0)       = re[k];
        *(f32x4*)(outp + (k0 + k) * 256 + 128 + i0) = im[k];
    }
}

// ---------------- per-mode channel mix, bf16x3 MFMA (in-place safe) ----------------
__global__ __launch_bounds__(256) void k_mixm(const float* __restrict__ A,
        const ushort* __restrict__ Wph, const ushort* __restrict__ Wpl,
        float* __restrict__ outF) {
    __shared__ ushort Ah[32 * 264];
    __shared__ ushort Al[32 * 264];
    int tid = threadIdx.x;
    int kt = blockIdx.x & 15;
    int bm0 = (blockIdx.x >> 4) * 32;
    {
        int row = tid >> 3, cg = tid & 7;
        const float* arow = A + (bm0 + row) * FROW + kt * 256 + cg * 32;
        ushort* ah = &Ah[row * 264 + cg * 32];
        ushort* al = &Al[row * 264 + cg * 32];
#pragma unroll
        for (int j = 0; j < 8; ++j) {
            f32x4 v = *(const f32x4*)(arow + j * 4);
            short4v h4, l4;
#pragma unroll
            for (int q = 0; q < 4; ++q) {
                ushort h = f2bf(v[q]);
                h4[q] = (short)h;
                l4[q] = (short)f2bf(v[q] - bf2f(h));
            }
            *(short4v*)(ah + j * 4) = h4;
            *(short4v*)(al + j * 4) = l4;
        }
    }
    __syncthreads();
    int lane = tid & 63, wid = tid >> 6;
    int frow = lane & 15, fk8 = (lane >> 4) * 8, fr4 = (lane >> 4) * 4;
    f32x4 acc[2][4];
#pragma unroll
    for (int a = 0; a < 2; ++a)
#pragma unroll
        for (int c = 0; c < 4; ++c) acc[a][c] = {0.f, 0.f, 0.f, 0.f};
    const ushort* wph = Wph + kt * 65536;
    const ushort* wpl = Wpl + kt * 65536;
#pragma unroll
    for (int kk = 0; kk < 8; ++kk) {
        short8 ah0 = *(const short8*)&Ah[(frow)      * 264 + kk * 32 + fk8];
        short8 ah1 = *(const short8*)&Ah[(16 + frow) * 264 + kk * 32 + fk8];
        short8 al0 = *(const short8*)&Al[(frow)      * 264 + kk * 32 + fk8];
        short8 al1 = *(const short8*)&Al[(16 + frow) * 264 + kk * 32 + fk8];
#pragma unroll
        for (int tc = 0; tc < 4; ++tc) {
            int op = wid * 64 + tc * 16 + frow;
            int base = op * 256 + kk * 32 + fk8;
            short8 wh = *(const short8*)&wph[base];
            short8 wl = *(const short8*)&wpl[base];
            acc[0][tc] = __builtin_amdgcn_mfma_f32_16x16x32_bf16(ah0, wh, acc[0][tc], 0, 0, 0);
            acc[0][tc] = __builtin_amdgcn_mfma_f32_16x16x32_bf16(ah0, wl, acc[0][tc], 0, 0, 0);
            acc[0][tc] = __builtin_amdgcn_mfma_f32_16x16x32_bf16(al0, wh, acc[0][tc], 0, 0, 0);
            acc[1][tc] = __builtin_amdgcn_mfma_f32_16x16x32_bf16(ah1, wh, acc[1][tc], 0, 0, 0);
            acc[1][tc] = __builtin_amdgcn_mfma_f32_16x16x32_bf16(ah1, wl, acc[1][tc], 0, 0, 0);
            acc[1][tc] = __builtin_amdgcn_mfma_f32_16x16x32_bf16(al1, wh, acc[1][tc], 0, 0, 0);
        }
    }
#pragma unroll
    for (int tr = 0; tr < 2; ++tr)
#pragma unroll
        for (int tc = 0; tc < 4; ++tc)
#pragma unroll
            for (int r = 0; r < 4; ++r)
                outF[(bm0 + tr * 16 + fr4 + r) * FROW + kt * 256 + wid * 64 + tc * 16 + frow]
                    = acc[tr][tc][r];
}

// ---------------- inverse DFT (4-wide over o, 4 n/thread, block 1024) ----------------
// og = tid&31 owns o4 = og*4; ng = tid>>5 (0..31) owns n = ng*4 + j (j<4).
// mode 0: y-branch, contiguous bf16 write. mode 1: f32 fallback.
// mode 2: x-branch fused branch-sum (scatter). mode 3: fallback scatter.
__global__ __launch_bounds__(1024) void k_icdft(const float* __restrict__ f,
        const float* __restrict__ IT, ushort* __restrict__ obf,
        float* __restrict__ h32, const ushort* __restrict__ hyin, int mode) {
    __shared__ float IT_s[128 * 32];
    __shared__ float f_s[32 * 128];
    int tid = threadIdx.x;
    int row = blockIdx.x;
    *(f32x4*)&IT_s[tid * 4] = *(const f32x4*)&IT[tid * 4];
    *(f32x4*)&f_s[tid * 4]  = *(const f32x4*)(f + (size_t)row * FROW + tid * 4);
    __syncthreads();
    int og = tid & 31, ng = tid >> 5;
    int o4 = og * 4;

    f32x4 acc[4];
#pragma unroll
    for (int j = 0; j < 4; ++j) acc[j] = {0.f, 0.f, 0.f, 0.f};

#pragma unroll
    for (int kpb = 0; kpb < 8; ++kpb) {
        int kp0 = kpb * 4;
        f32x4 fv0 = *(const f32x4*)&f_s[(kp0 + 0) * 128 + o4];
        f32x4 fv1 = *(const f32x4*)&f_s[(kp0 + 1) * 128 + o4];
        f32x4 fv2 = *(const f32x4*)&f_s[(kp0 + 2) * 128 + o4];
        f32x4 fv3 = *(const f32x4*)&f_s[(kp0 + 3) * 128 + o4];
#pragma unroll
        for (int j = 0; j < 4; ++j) {
            int n = ng * 4 + j;
            f32x4 it = *(const f32x4*)&IT_s[n * 32 + kp0];
#pragma unroll
            for (int q = 0; q < 4; ++q)
                acc[j][q] += fv0[q] * it[0] + fv1[q] * it[1]
                           + fv2[q] * it[2] + fv3[q] * it[3];
        }
    }

    if (mode == 0) {
#pragma unroll
        for (int j = 0; j < 4; ++j) {
            int n = ng * 4 + j;
            ushort4v t;
#pragma unroll
            for (int q = 0; q < 4; ++q) t[q] = f2bf(acc[j][q]);
            *(ushort4v*)&obf[(size_t)row * HROW + n * 128 + o4] = t;
        }
    } else if (mode == 1) {
#pragma unroll
        for (int j = 0; j < 4; ++j) {
            int n = ng * 4 + j;
            *(f32x4*)&h32[(size_t)row * HROW + n * 128 + o4] = acc[j];
        }
    } else if (mode == 2) {
        size_t base = (size_t)(row >> 7) * 2097152 + (size_t)(row & 127) * 128 + o4;
#pragma unroll
        for (int j = 0; j < 4; ++j) {
            int n = ng * 4 + j;
            size_t ix = base + (size_t)n * 16384;
            ushort4v hv = *(const ushort4v*)&hyin[ix];
            ushort4v t;
#pragma unroll
            for (int q = 0; q < 4; ++q) t[q] = f2bf(bf2f(hv[q]) + acc[j][q]);
            *(ushort4v*)&obf[ix] = t;
        }
    } else {
        size_t base = (size_t)(row >> 7) * 2097152 + (size_t)(row & 127) * 128 + o4;
#pragma unroll
        for (int j = 0; j < 4; ++j) {
            int n = ng * 4 + j;
            size_t ix = base + (size_t)n * 16384;
            f32x4 hv = *(const f32x4*)&h32[ix];
            ushort4v t;
#pragma unroll
            for (int q = 0; q < 4; ++q) t[q] = f2bf(hv[q] + acc[j][q]);
            *(ushort4v*)&obf[ix] = t;
        }
    }
}

// ---------------- GEMM1 + ReLU: h1 = relu(h @ w0 + b0), bf16 out ----------------
// Per chunk: tile 128 rows x 64 hcols, K=128 staged once, padded LDS.
// Grid = (chunk_rows/128) * 8.
__global__ __launch_bounds__(256) void k_ffn1(const ushort* __restrict__ hin,
        const ushort* __restrict__ w0t, const float* __restrict__ b0,
        ushort* __restrict__ h1o) {
    __shared__ ushort A_l[128 * 136];   // 34816 B, rows 272 B (16B-aligned)
    __shared__ ushort B_l[64 * 136];    // 17408 B
    int tid = threadIdx.x;
    int ht = blockIdx.x & 7, rt = blockIdx.x >> 3;
    int R0 = rt * 128, H0 = ht * 64;

#pragma unroll
    for (int i = 0; i < 8; ++i) {       // A: 2048 ushort8 groups
        int e = tid + i * 256;
        int row = e >> 4, c16 = e & 15;
        *(ushort8*)&A_l[row * 136 + c16 * 8] =
            *(const ushort8*)(hin + (size_t)(R0 + row) * 128 + c16 * 8);
    }
#pragma unroll
    for (int i = 0; i < 4; ++i) {       // B: 1024 groups
        int e = tid + i * 256;
        int row = e >> 4, c16 = e & 15;
        *(ushort8*)&B_l[row * 136 + c16 * 8] =
            *(const ushort8*)(w0t + (H0 + row) * 128 + c16 * 8);
    }
    __syncthreads();

    int lane = tid & 63, wave = tid >> 6;
    int frow = lane & 15, qg = lane >> 4, fk8 = qg * 8, fr4 = qg * 4;
    int r2 = wave >> 1, c2 = wave & 1;   // 2x2 wave grid: 64 rows x 32 hcols each

    f32x4 acc[4][2];
#pragma unroll
    for (int a = 0; a < 4; ++a)
#pragma unroll
        for (int c = 0; c < 2; ++c) acc[a][c] = {0.f, 0.f, 0.f, 0.f};

#pragma unroll
    for (int kk = 0; kk < 4; ++kk) {
        short8 af[4], bf[2];
#pragma unroll
        for (int tr = 0; tr < 4; ++tr)
            af[tr] = *(const short8*)&A_l[(r2 * 64 + tr * 16 + frow) * 136 + kk * 32 + fk8];
#pragma unroll
        for (int tc = 0; tc < 2; ++tc)
            bf[tc] = *(const short8*)&B_l[(c2 * 32 + tc * 16 + frow) * 136 + kk * 32 + fk8];
#pragma unroll
        for (int tr = 0; tr < 4; ++tr)
#pragma unroll
            for (int tc = 0; tc < 2; ++tc)
                acc[tr][tc] = __builtin_amdgcn_mfma_f32_16x16x32_bf16(
                    af[tr], bf[tc], acc[tr][tc], 0, 0, 0);
    }

    float b0v[2];
    b0v[0] = b0[H0 + c2 * 32 + frow];
    b0v[1] = b0[H0 + c2 * 32 + 16 + frow];
#pragma unroll
    for (int tr = 0; tr < 4; ++tr)
#pragma unroll
        for (int tc = 0; tc < 2; ++tc)
#pragma unroll
            for (int r = 0; r < 4; ++r) {
                int row = r2 * 64 + tr * 16 + fr4 + r;
                int col = H0 + c2 * 32 + tc * 16 + frow;
                h1o[(size_t)(R0 + row) * 512 + col] =
                    f2bf(fmaxf(acc[tr][tc][r] + b0v[tc], 0.f));
            }
}

// ---------------- GEMM2 + bias + LayerNorm: out = LN(h1 @ w1 + b1) ----------------
// Per chunk: tile 32 rows x 128 cols (full row -> LN fused). 8 K-steps of 64;
// single-buffered padded LDS; register prefetch of next tile; 2 barriers/step.
// Grid = chunk_rows/32.
__global__ __launch_bounds__(256) void k_ffn2(const ushort* __restrict__ h1,
        const ushort* __restrict__ w1t, const float* __restrict__ b1,
        const float* __restrict__ g, const float* __restrict__ bb,
        float* __restrict__ out) {
    __shared__ ushort A_l[32 * 72];     // 4608 B, rows 144 B (16B-aligned)
    __shared__ ushort B_l[128 * 72];    // 18432 B
    __shared__ float ps_s[128];
    __shared__ float pq_s[128];
    int tid = threadIdx.x;
    int R0 = blockIdx.x * 32;
    int lane = tid & 63, wave = tid >> 6;
    int frow = lane & 15, qg = lane >> 4, fk8 = qg * 8, fr4 = qg * 4;
    int sAr = tid >> 3, sc8 = tid & 7;  // A-stage: 1 group/thread; B-stage: 4 rows, +32 apart

    // prologue: stage kt=0
    *(ushort8*)&A_l[sAr * 72 + sc8 * 8] =
        *(const ushort8*)(h1 + (size_t)(R0 + sAr) * 512 + sc8 * 8);
#pragma unroll
    for (int i = 0; i < 4; ++i) {
        int ro = sAr + i * 32;
        *(ushort8*)&B_l[ro * 72 + sc8 * 8] =
            *(const ushort8*)(w1t + ro * 512 + sc8 * 8);
    }
    __syncthreads();

    f32x4 acc[2][2];
#pragma unroll
    for (int a = 0; a < 2; ++a)
#pragma unroll
        for (int c = 0; c < 2; ++c) acc[a][c] = {0.f, 0.f, 0.f, 0.f};

#pragma unroll 1
    for (int kt = 0; kt < 8; ++kt) {
        // prefetch next K-tile into named registers (issued before MFMAs)
        ushort8 sa, sb0, sb1, sb2, sb3;
        if (kt < 7) {
            int koff = (kt + 1) * 64 + sc8 * 8;
            sa  = *(const ushort8*)(h1 + (size_t)(R0 + sAr) * 512 + koff);
            sb0 = *(const ushort8*)(w1t + (sAr +  0) * 512 + koff);
            sb1 = *(const ushort8*)(w1t + (sAr + 32) * 512 + koff);
            sb2 = *(const ushort8*)(w1t + (sAr + 64) * 512 + koff);
            sb3 = *(const ushort8*)(w1t + (sAr + 96) * 512 + koff);
        }
        // MFMA over current tile
#pragma unroll
        for (int kk = 0; kk < 2; ++kk) {
            short8 af[2], bf[2];
#pragma unroll
            for (int tr = 0; tr < 2; ++tr)
                af[tr] = *(const short8*)&A_l[(tr * 16 + frow) * 72 + kk * 32 + fk8];
#pragma unroll
            for (int tc = 0; tc < 2; ++tc)
                bf[tc] = *(const short8*)&B_l[(wave * 32 + tc * 16 + frow) * 72 + kk * 32 + fk8];
#pragma unroll
            for (int tr = 0; tr < 2; ++tr)
#pragma unroll
                for (int tc = 0; tc < 2; ++tc)
                    acc[tr][tc] = __builtin_amdgcn_mfma_f32_16x16x32_bf16(
                        af[tr], bf[tc], acc[tr][tc], 0, 0, 0);
        }
        __syncthreads();   // all waves done reading this K-tile
        if (kt < 7) {
            *(ushort8*)&A_l[sAr * 72 + sc8 * 8] = sa;
            *(ushort8*)&B_l[(sAr +  0) * 72 + sc8 * 8] = sb0;
            *(ushort8*)&B_l[(sAr + 32) * 72 + sc8 * 8] = sb1;
            *(ushort8*)&B_l[(sAr + 64) * 72 + sc8 * 8] = sb2;
            *(ushort8*)&B_l[(sAr + 96) * 72 + sc8 * 8] = sb3;
            __syncthreads();   // next K-tile visible
        }
    }

    // ---- epilogue: +b1, per-wave LN partials, cross-wave combine, stores ----
    float b1v[2], gv[2], bv[2];
#pragma unroll
    for (int tc = 0; tc < 2; ++tc) {
        int o = wave * 32 + tc * 16 + frow;
        b1v[tc] = b1[o]; gv[tc] = g[o]; bv[tc] = bb[o];
    }
#pragma unroll
    for (int tr = 0; tr < 2; ++tr)
#pragma unroll
        for (int r = 0; r < 4; ++r) {
            float s = 0.f, qq = 0.f;
#pragma unroll
            for (int tc = 0; tc < 2; ++tc) {
                float v = acc[tr][tc][r] + b1v[tc];
                acc[tr][tc][r] = v;
                s += v; qq += v * v;
            }
            s += __shfl_xor(s, 1); qq += __shfl_xor(qq, 1);
            s += __shfl_xor(s, 2); qq += __shfl_xor(qq, 2);
            s += __shfl_xor(s, 4); qq += __shfl_xor(qq, 4);
            s += __shfl_xor(s, 8); qq += __shfl_xor(qq, 8);
            if (frow == 0) {
                int row = tr * 16 + fr4 + r;
                ps_s[wave * 32 + row] = s;
                pq_s[wave * 32 + row] = qq;
            }
        }
    __syncthreads();
#pragma unroll
    for (int tr = 0; tr < 2; ++tr)
#pragma unroll
        for (int r = 0; r < 4; ++r) {
            int row = tr * 16 + fr4 + r;
            float S = ps_s[row] + ps_s[32 + row] + ps_s[64 + row] + ps_s[96 + row];
            float Q = pq_s[row] + pq_s[32 + row] + pq_s[64 + row] + pq_s[96 + row];
            float mu = S * (1.0f / 128.0f);
            float var = Q * (1.0f / 128.0f) - mu * mu;
            float rs = rsqrtf(fmaxf(var, 0.f) + LN_EPS);
            float* orow = &out[(size_t)(R0 + row) * 128 + wave * 32];
            orow[frow]      = (acc[tr][0][r] - mu) * rs * gv[0] + bv[0];
            orow[16 + frow] = (acc[tr][1][r] - mu) * rs * gv[1] + bv[1];
        }
}

extern "C" void kernel_launch(void* const* d_in, const int* in_sizes, int n_in,
                              void* d_out, int out_size, void* d_ws, size_t ws_size,
                              hipStream_t stream) {
    (void)in_sizes; (void)n_in; (void)out_size;
    const float* x   = (const float*)d_in[0];
    const float* w1  = (const float*)d_in[1];
    const float* w2  = (const float*)d_in[2];
    const float* fw0 = (const float*)d_in[3];
    const float* fb0 = (const float*)d_in[4];
    const float* fw1 = (const float*)d_in[5];
    const float* fb1 = (const float*)d_in[6];
    const float* lng = (const float*)d_in[7];
    const float* lnb = (const float*)d_in[8];
    float* out = (float*)d_out;

    char* ws = (char*)d_ws;
    float*  Tc  = (float*)(ws);
    float*  Ts  = (float*)(ws + 8192);
    float*  IT  = (float*)(ws + 16384);
    ushort* Wph = (ushort*)(ws + 32768);                  // 2 MB
    ushort* Wpl = (ushort*)(ws + 32768 + 2097152);        // 2 MB
    ushort* w0t = (ushort*)(ws + 4227072);                // 128 KB
    ushort* w1t = (ushort*)(ws + 4358144);                // 128 KB
    float*  buf0 = (float*)(ws + 4489216);                // F/f (32 MiB, in-place mix)
    ushort* hy   = (ushort*)(ws + 38043648);              // 64 MiB
    ushort* hsum = (ushort*)(ws + 105152512);             // 64 MiB
    const size_t need_two = 172261376ull;
    int two = (ws_size >= need_two) ? 1 : 0;
    ushort* hbfs = hy;   // fallback single-buffer

    k_setup<<<1, 256, 0, stream>>>(Tc, Ts, IT);
    k_wcvt <<<256, 256, 0, stream>>>(fw0, fw1, w0t, w1t);

    // y-branch: DFT over n, mix with w1, inverse over n -> hy[b,m,n,o] bf16
    k_wpack<<<4096, 256, 0, stream>>>(w1, Wph, Wpl);
    k_fft  <<<2048, 128, 0, stream>>>(x, Tc, Ts, buf0, 0);
    k_mixm <<<1024, 256, 0, stream>>>(buf0, Wph, Wpl, buf0);
    if (two) k_icdft<<<2048, 1024, 0, stream>>>(buf0, IT, hy, out, hy, 0);
    else     k_icdft<<<2048, 1024, 0, stream>>>(buf0, IT, hy, out, hy, 1);

    // x-branch: DFT over m, mix with w2, inverse over m; fused h = hy + hx -> hsum
    k_wpack<<<4096, 256, 0, stream>>>(w2, Wph, Wpl);
    k_fft  <<<2048, 128, 0, stream>>>(x, Tc, Ts, buf0, 1);
    k_mixm <<<1024, 256, 0, stream>>>(buf0, Wph, Wpl, buf0);
    if (two) k_icdft<<<2048, 1024, 0, stream>>>(buf0, IT, hsum, out, hy, 2);
    else     k_icdft<<<2048, 1024, 0, stream>>>(buf0, IT, hbfs, out, hy, 3);

    // FFN as two GEMMs over 262144 rows, chunked so h1 fits a dead ws buffer.
    if (two) {
        // 4 chunks x 65536 rows; h1 chunk = 64 MiB = exactly the dead hy region.
        for (int c = 0; c < 4; ++c) {
            const size_t off = (size_t)c * 65536 * 128;
            k_ffn1<<<4096, 256, 0, stream>>>(hsum + off, w0t, fb0, hy);
            k_ffn2<<<2048, 256, 0, stream>>>(hy, w1t, fb1, lng, lnb, out + off);
        }
    } else {
        // 8 chunks x 32768 rows; h1 chunk = 32 MiB = exactly buf0 (dead).
        ushort* h1buf = (ushort*)buf0;
        for (int c = 0; c < 8; ++c) {
            const size_t off = (size_t)c * 32768 * 128;
            k_ffn1<<<2048, 256, 0, stream>>>(hbfs + off, w0t, fb0, h1buf);
            k_ffn2<<<1024, 256, 0, stream>>>(h1buf, w1t, fb1, lng, lnb, out + off);
        }
    }
}

// Round 16
// 502.026 us; speedup vs baseline: 1.1783x; 1.1783x over previous
//
#include <hip/hip_runtime.h>

// Geo-FFNO forward: factored Fourier (DFT -> per-mode complex mix -> iDFT, 16 modes)
// + FFN (Linear 128->512, ReLU, Linear 512->128, +bias, LayerNorm).
// B=16, M=N=128, D=I=O=128, NM=16, H=512.  FFN row count M_total = 16*128*128 = 262144.
//
// R16: k_fft -> bf16x3 MFMA GEMM (F[kp][i] = sum_n T2[kp][n] x[n][i] per slab).
// Three prior k_fft forms hit ~70-87us on LDS-instr / occupancy / HBM-reread walls;
// MFMA reads x once, tables as tiny A-frags. T2 pre-split hi/lo in k_setup (same
// ws slots as old Tc/Ts; F layout unchanged). Everything else identical to R15.

#define LN_EPS 1e-5f
#define NMODES 16
#define FROW 4096     // per-row F/f size: 16k * 2 * 128
#define HROW 16384    // per (b,m) h row: 128*128

typedef __attribute__((ext_vector_type(8))) short short8;
typedef __attribute__((ext_vector_type(8))) ushort ushort8;
typedef __attribute__((ext_vector_type(4))) ushort ushort4v;
typedef __attribute__((ext_vector_type(4))) short short4v;
typedef __attribute__((ext_vector_type(4))) float f32x4;

__device__ __forceinline__ ushort f2bf(float f) {
    unsigned u = __float_as_uint(f);
    unsigned r = (u + 0x7FFFu + ((u >> 16) & 1u)) >> 16;   // RNE
    return (ushort)r;
}
__device__ __forceinline__ float bf2f(ushort h) {
    return __uint_as_float(((unsigned)h) << 16);
}

// ---------------- tables ----------------
// T2[kp][n], kp<32: kp=2k -> cos(2*pi*k*n/128)/sqrt(128); kp=2k+1 -> -sin(...)/sqrt(128).
// Stored as bf16 hi/lo pair. IT unchanged (irfft semantics).
__global__ void k_setup(ushort* __restrict__ T2h, ushort* __restrict__ T2l,
                        float* __restrict__ IT) {
    const float invs = 0.08838834764831845f;  // 1/sqrt(128)
    for (int idx = threadIdx.x; idx < 32 * 128; idx += blockDim.x) {
        int kp = idx >> 7, n = idx & 127;
        int k = kp >> 1;
        int p = (k * n) & 127;
        float th = (float)p * (6.283185307179586f / 128.0f);
        float v = (kp & 1) ? (-sinf(th) * invs) : (cosf(th) * invs);
        ushort hi = f2bf(v);
        T2h[idx] = hi;
        T2l[idx] = f2bf(v - bf2f(hi));
    }
    for (int idx = threadIdx.x; idx < NMODES * 128; idx += blockDim.x) {
        int k = idx >> 7, n = idx & 127;
        int p = (k * n) & 127;
        float th = (float)p * (6.283185307179586f / 128.0f);
        float ck = (k == 0) ? invs : 2.0f * invs;
        IT[n * 32 + 2 * k]     = ck * cosf(th);
        IT[n * 32 + 2 * k + 1] = -ck * sinf(th);
    }
}

// ---------------- packed complex-mix weights, transposed, bf16 hi/lo ----------------
// Layout: [k][op][ip]; value(ip,op): ip<128: (op<128? re : im); ip>=128: (op<128? -im : re)
__global__ void k_wpack(const float* __restrict__ w, ushort* __restrict__ Wph,
                        ushort* __restrict__ Wpl) {
    int idx = blockIdx.x * 256 + threadIdx.x;  // 16*256*256 = 1,048,576
    int k  = idx >> 16;
    int op = (idx >> 8) & 255;
    int ip = idx & 255;
    int i = ip & 127, o = op & 127;
    const float* base = w + (((i << 7) | o) * NMODES + k) * 2;
    float re = base[0], im = base[1];
    float v = (ip < 128) ? ((op < 128) ? re : im)
                         : ((op < 128) ? -im : re);
    ushort hi = f2bf(v);
    ushort lo = f2bf(v - bf2f(hi));
    Wph[idx] = hi;
    Wpl[idx] = lo;
}

// ---------------- bf16 FFN weights (once) ----------------
// w0t[h][k] = w0[k][h]  (512x128 bf16); w1t[o][h] = w1[h][o]  (128x512 bf16)
__global__ __launch_bounds__(256) void k_wcvt(const float* __restrict__ w0,
        const float* __restrict__ w1, ushort* __restrict__ w0t,
        ushort* __restrict__ w1t) {
    int idx = blockIdx.x * 256 + threadIdx.x;   // 65536
    int h = idx >> 7, k = idx & 127;
    w0t[idx] = f2bf(w0[k * 512 + h]);
    int o = idx >> 9, hh = idx & 511;
    w1t[idx] = f2bf(w1[hh * 128 + o]);
}

// ---------------- truncated forward DFT via MFMA ----------------
// One slab per block (256 thr, 4 waves). F_slab[32 kp x 128 i] = T2[32x128] @ Xslab[128x128].
// 4 chunks of 32 n: pair-transposed hi/lo staging into Xh/Xl [128 i][38 n-pad],
// A-frags from global T2h/T2l, 12 MFMA/chunk/wave (bf16x3).
__global__ __launch_bounds__(256) void k_fft(const float* __restrict__ x,
        const ushort* __restrict__ T2h, const ushort* __restrict__ T2l,
        float* __restrict__ F, int mode) {
    __shared__ ushort Xh[128 * 38];   // 9728 B, row stride 38 ushort (19 uint)
    __shared__ ushort Xl[128 * 38];
    int tid = threadIdx.x;
    int slab = blockIdx.x;
    size_t base; int ts;
    if (mode == 0) { base = (size_t)slab * HROW; ts = 128; }
    else { base = (size_t)(slab >> 7) * 2097152 + (size_t)(slab & 127) * 128; ts = 16384; }

    int sr2 = tid >> 4, sc = tid & 15;     // staging: row-pair, i-group of 8
    int lane = tid & 63, w = tid >> 6;
    int frow = lane & 15, fk8 = (lane >> 4) * 8, fr4 = (lane >> 4) * 4;

    f32x4 acc[2][2];
#pragma unroll
    for (int a = 0; a < 2; ++a)
#pragma unroll
        for (int c = 0; c < 2; ++c) acc[a][c] = {0.f, 0.f, 0.f, 0.f};

#pragma unroll 1
    for (int nc = 0; nc < 4; ++nc) {
        if (nc) __syncthreads();   // prior chunk's frag reads done
        {   // stage chunk rows [nc*32, nc*32+32), pair-transposed, hi/lo
            const float* pa = x + base + (size_t)(nc * 32 + 2 * sr2) * ts + sc * 8;
            const float* pb = pa + ts;
            f32x4 a0 = *(const f32x4*)pa;
            f32x4 a1 = *(const f32x4*)(pa + 4);
            f32x4 b0 = *(const f32x4*)pb;
            f32x4 b1 = *(const f32x4*)(pb + 4);
            uint* xh32 = (uint*)Xh;
            uint* xl32 = (uint*)Xl;
#pragma unroll
            for (int q = 0; q < 8; ++q) {
                float av = (q < 4) ? a0[q] : a1[q - 4];
                float bv = (q < 4) ? b0[q] : b1[q - 4];
                ushort ah = f2bf(av), bh = f2bf(bv);
                ushort al = f2bf(av - bf2f(ah)), bl = f2bf(bv - bf2f(bh));
                int i = sc * 8 + q;
                xh32[i * 19 + sr2] = (uint)ah | ((uint)bh << 16);
                xl32[i * 19 + sr2] = (uint)al | ((uint)bl << 16);
            }
        }
        __syncthreads();
        // frags + MFMA
        short8 ah_[2], al_[2], bh_[2], bl_[2];
#pragma unroll
        for (int kt = 0; kt < 2; ++kt) {
            int ro = (kt * 16 + frow) * 128 + nc * 32 + fk8;
            ah_[kt] = *(const short8*)&T2h[ro];
            al_[kt] = *(const short8*)&T2l[ro];
        }
#pragma unroll
        for (int it = 0; it < 2; ++it) {
            int i = w * 32 + it * 16 + frow;
            bh_[it] = *(const short8*)&Xh[i * 38 + fk8];
            bl_[it] = *(const short8*)&Xl[i * 38 + fk8];
        }
#pragma unroll
        for (int kt = 0; kt < 2; ++kt)
#pragma unroll
            for (int it = 0; it < 2; ++it) {
                acc[kt][it] = __builtin_amdgcn_mfma_f32_16x16x32_bf16(
                    ah_[kt], bh_[it], acc[kt][it], 0, 0, 0);
                acc[kt][it] = __builtin_amdgcn_mfma_f32_16x16x32_bf16(
                    ah_[kt], bl_[it], acc[kt][it], 0, 0, 0);
                acc[kt][it] = __builtin_amdgcn_mfma_f32_16x16x32_bf16(
                    al_[kt], bh_[it], acc[kt][it], 0, 0, 0);
            }
    }

    float* outp = F + (size_t)slab * FROW;
#pragma unroll
    for (int kt = 0; kt < 2; ++kt)
#pragma unroll
        for (int it = 0; it < 2; ++it)
#pragma unroll
            for (int r = 0; r < 4; ++r)
                outp[(kt * 16 + fr4 + r) * 128 + w * 32 + it * 16 + frow] = acc[kt][it][r];
}

// ---------------- per-mode channel mix, bf16x3 MFMA (in-place safe) ----------------
__global__ __launch_bounds__(256) void k_mixm(const float* __restrict__ A,
        const ushort* __restrict__ Wph, const ushort* __restrict__ Wpl,
        float* __restrict__ outF) {
    __shared__ ushort Ah[32 * 264];
    __shared__ ushort Al[32 * 264];
    int tid = threadIdx.x;
    int kt = blockIdx.x & 15;
    int bm0 = (blockIdx.x >> 4) * 32;
    {
        int row = tid >> 3, cg = tid & 7;
        const float* arow = A + (bm0 + row) * FROW + kt * 256 + cg * 32;
        ushort* ah = &Ah[row * 264 + cg * 32];
        ushort* al = &Al[row * 264 + cg * 32];
#pragma unroll
        for (int j = 0; j < 8; ++j) {
            f32x4 v = *(const f32x4*)(arow + j * 4);
            short4v h4, l4;
#pragma unroll
            for (int q = 0; q < 4; ++q) {
                ushort h = f2bf(v[q]);
                h4[q] = (short)h;
                l4[q] = (short)f2bf(v[q] - bf2f(h));
            }
            *(short4v*)(ah + j * 4) = h4;
            *(short4v*)(al + j * 4) = l4;
        }
    }
    __syncthreads();
    int lane = tid & 63, wid = tid >> 6;
    int frow = lane & 15, fk8 = (lane >> 4) * 8, fr4 = (lane >> 4) * 4;
    f32x4 acc[2][4];
#pragma unroll
    for (int a = 0; a < 2; ++a)
#pragma unroll
        for (int c = 0; c < 4; ++c) acc[a][c] = {0.f, 0.f, 0.f, 0.f};
    const ushort* wph = Wph + kt * 65536;
    const ushort* wpl = Wpl + kt * 65536;
#pragma unroll
    for (int kk = 0; kk < 8; ++kk) {
        short8 ah0 = *(const short8*)&Ah[(frow)      * 264 + kk * 32 + fk8];
        short8 ah1 = *(const short8*)&Ah[(16 + frow) * 264 + kk * 32 + fk8];
        short8 al0 = *(const short8*)&Al[(frow)      * 264 + kk * 32 + fk8];
        short8 al1 = *(const short8*)&Al[(16 + frow) * 264 + kk * 32 + fk8];
#pragma unroll
        for (int tc = 0; tc < 4; ++tc) {
            int op = wid * 64 + tc * 16 + frow;
            int base = op * 256 + kk * 32 + fk8;
            short8 wh = *(const short8*)&wph[base];
            short8 wl = *(const short8*)&wpl[base];
            acc[0][tc] = __builtin_amdgcn_mfma_f32_16x16x32_bf16(ah0, wh, acc[0][tc], 0, 0, 0);
            acc[0][tc] = __builtin_amdgcn_mfma_f32_16x16x32_bf16(ah0, wl, acc[0][tc], 0, 0, 0);
            acc[0][tc] = __builtin_amdgcn_mfma_f32_16x16x32_bf16(al0, wh, acc[0][tc], 0, 0, 0);
            acc[1][tc] = __builtin_amdgcn_mfma_f32_16x16x32_bf16(ah1, wh, acc[1][tc], 0, 0, 0);
            acc[1][tc] = __builtin_amdgcn_mfma_f32_16x16x32_bf16(ah1, wl, acc[1][tc], 0, 0, 0);
            acc[1][tc] = __builtin_amdgcn_mfma_f32_16x16x32_bf16(al1, wh, acc[1][tc], 0, 0, 0);
        }
    }
#pragma unroll
    for (int tr = 0; tr < 2; ++tr)
#pragma unroll
        for (int tc = 0; tc < 4; ++tc)
#pragma unroll
            for (int r = 0; r < 4; ++r)
                outF[(bm0 + tr * 16 + fr4 + r) * FROW + kt * 256 + wid * 64 + tc * 16 + frow]
                    = acc[tr][tc][r];
}

// ---------------- inverse DFT (4-wide over o, 4 n/thread, block 1024) ----------------
// og = tid&31 owns o4 = og*4; ng = tid>>5 (0..31) owns n = ng*4 + j (j<4).
// mode 0: y-branch, contiguous bf16 write. mode 1: f32 fallback.
// mode 2: x-branch fused branch-sum (scatter). mode 3: fallback scatter.
__global__ __launch_bounds__(1024) void k_icdft(const float* __restrict__ f,
        const float* __restrict__ IT, ushort* __restrict__ obf,
        float* __restrict__ h32, const ushort* __restrict__ hyin, int mode) {
    __shared__ float IT_s[128 * 32];
    __shared__ float f_s[32 * 128];
    int tid = threadIdx.x;
    int row = blockIdx.x;
    *(f32x4*)&IT_s[tid * 4] = *(const f32x4*)&IT[tid * 4];
    *(f32x4*)&f_s[tid * 4]  = *(const f32x4*)(f + (size_t)row * FROW + tid * 4);
    __syncthreads();
    int og = tid & 31, ng = tid >> 5;
    int o4 = og * 4;

    f32x4 acc[4];
#pragma unroll
    for (int j = 0; j < 4; ++j) acc[j] = {0.f, 0.f, 0.f, 0.f};

#pragma unroll
    for (int kpb = 0; kpb < 8; ++kpb) {
        int kp0 = kpb * 4;
        f32x4 fv0 = *(const f32x4*)&f_s[(kp0 + 0) * 128 + o4];
        f32x4 fv1 = *(const f32x4*)&f_s[(kp0 + 1) * 128 + o4];
        f32x4 fv2 = *(const f32x4*)&f_s[(kp0 + 2) * 128 + o4];
        f32x4 fv3 = *(const f32x4*)&f_s[(kp0 + 3) * 128 + o4];
#pragma unroll
        for (int j = 0; j < 4; ++j) {
            int n = ng * 4 + j;
            f32x4 it = *(const f32x4*)&IT_s[n * 32 + kp0];
#pragma unroll
            for (int q = 0; q < 4; ++q)
                acc[j][q] += fv0[q] * it[0] + fv1[q] * it[1]
                           + fv2[q] * it[2] + fv3[q] * it[3];
        }
    }

    if (mode == 0) {
#pragma unroll
        for (int j = 0; j < 4; ++j) {
            int n = ng * 4 + j;
            ushort4v t;
#pragma unroll
            for (int q = 0; q < 4; ++q) t[q] = f2bf(acc[j][q]);
            *(ushort4v*)&obf[(size_t)row * HROW + n * 128 + o4] = t;
        }
    } else if (mode == 1) {
#pragma unroll
        for (int j = 0; j < 4; ++j) {
            int n = ng * 4 + j;
            *(f32x4*)&h32[(size_t)row * HROW + n * 128 + o4] = acc[j];
        }
    } else if (mode == 2) {
        size_t base = (size_t)(row >> 7) * 2097152 + (size_t)(row & 127) * 128 + o4;
#pragma unroll
        for (int j = 0; j < 4; ++j) {
            int n = ng * 4 + j;
            size_t ix = base + (size_t)n * 16384;
            ushort4v hv = *(const ushort4v*)&hyin[ix];
            ushort4v t;
#pragma unroll
            for (int q = 0; q < 4; ++q) t[q] = f2bf(bf2f(hv[q]) + acc[j][q]);
            *(ushort4v*)&obf[ix] = t;
        }
    } else {
        size_t base = (size_t)(row >> 7) * 2097152 + (size_t)(row & 127) * 128 + o4;
#pragma unroll
        for (int j = 0; j < 4; ++j) {
            int n = ng * 4 + j;
            size_t ix = base + (size_t)n * 16384;
            f32x4 hv = *(const f32x4*)&h32[ix];
            ushort4v t;
#pragma unroll
            for (int q = 0; q < 4; ++q) t[q] = f2bf(hv[q] + acc[j][q]);
            *(ushort4v*)&obf[ix] = t;
        }
    }
}

// ---------------- GEMM1 + ReLU: h1 = relu(h @ w0 + b0), bf16 out ----------------
// Per chunk: tile 128 rows x 64 hcols, K=128 staged once, padded LDS.
// Grid = (chunk_rows/128) * 8.
__global__ __launch_bounds__(256) void k_ffn1(const ushort* __restrict__ hin,
        const ushort* __restrict__ w0t, const float* __restrict__ b0,
        ushort* __restrict__ h1o) {
    __shared__ ushort A_l[128 * 136];   // 34816 B, rows 272 B (16B-aligned)
    __shared__ ushort B_l[64 * 136];    // 17408 B
    int tid = threadIdx.x;
    int ht = blockIdx.x & 7, rt = blockIdx.x >> 3;
    int R0 = rt * 128, H0 = ht * 64;

#pragma unroll
    for (int i = 0; i < 8; ++i) {       // A: 2048 ushort8 groups
        int e = tid + i * 256;
        int row = e >> 4, c16 = e & 15;
        *(ushort8*)&A_l[row * 136 + c16 * 8] =
            *(const ushort8*)(hin + (size_t)(R0 + row) * 128 + c16 * 8);
    }
#pragma unroll
    for (int i = 0; i < 4; ++i) {       // B: 1024 groups
        int e = tid + i * 256;
        int row = e >> 4, c16 = e & 15;
        *(ushort8*)&B_l[row * 136 + c16 * 8] =
            *(const ushort8*)(w0t + (H0 + row) * 128 + c16 * 8);
    }
    __syncthreads();

    int lane = tid & 63, wave = tid >> 6;
    int frow = lane & 15, qg = lane >> 4, fk8 = qg * 8, fr4 = qg * 4;
    int r2 = wave >> 1, c2 = wave & 1;   // 2x2 wave grid: 64 rows x 32 hcols each

    f32x4 acc[4][2];
#pragma unroll
    for (int a = 0; a < 4; ++a)
#pragma unroll
        for (int c = 0; c < 2; ++c) acc[a][c] = {0.f, 0.f, 0.f, 0.f};

#pragma unroll
    for (int kk = 0; kk < 4; ++kk) {
        short8 af[4], bf[2];
#pragma unroll
        for (int tr = 0; tr < 4; ++tr)
            af[tr] = *(const short8*)&A_l[(r2 * 64 + tr * 16 + frow) * 136 + kk * 32 + fk8];
#pragma unroll
        for (int tc = 0; tc < 2; ++tc)
            bf[tc] = *(const short8*)&B_l[(c2 * 32 + tc * 16 + frow) * 136 + kk * 32 + fk8];
#pragma unroll
        for (int tr = 0; tr < 4; ++tr)
#pragma unroll
            for (int tc = 0; tc < 2; ++tc)
                acc[tr][tc] = __builtin_amdgcn_mfma_f32_16x16x32_bf16(
                    af[tr], bf[tc], acc[tr][tc], 0, 0, 0);
    }

    float b0v[2];
    b0v[0] = b0[H0 + c2 * 32 + frow];
    b0v[1] = b0[H0 + c2 * 32 + 16 + frow];
#pragma unroll
    for (int tr = 0; tr < 4; ++tr)
#pragma unroll
        for (int tc = 0; tc < 2; ++tc)
#pragma unroll
            for (int r = 0; r < 4; ++r) {
                int row = r2 * 64 + tr * 16 + fr4 + r;
                int col = H0 + c2 * 32 + tc * 16 + frow;
                h1o[(size_t)(R0 + row) * 512 + col] =
                    f2bf(fmaxf(acc[tr][tc][r] + b0v[tc], 0.f));
            }
}

// ---------------- GEMM2 + bias + LayerNorm: out = LN(h1 @ w1 + b1) ----------------
// Per chunk: tile 32 rows x 128 cols (full row -> LN fused). 8 K-steps of 64;
// single-buffered padded LDS; register prefetch of next tile; 2 barriers/step.
// Grid = chunk_rows/32.
__global__ __launch_bounds__(256) void k_ffn2(const ushort* __restrict__ h1,
        const ushort* __restrict__ w1t, const float* __restrict__ b1,
        const float* __restrict__ g, const float* __restrict__ bb,
        float* __restrict__ out) {
    __shared__ ushort A_l[32 * 72];     // 4608 B, rows 144 B (16B-aligned)
    __shared__ ushort B_l[128 * 72];    // 18432 B
    __shared__ float ps_s[128];
    __shared__ float pq_s[128];
    int tid = threadIdx.x;
    int R0 = blockIdx.x * 32;
    int lane = tid & 63, wave = tid >> 6;
    int frow = lane & 15, qg = lane >> 4, fk8 = qg * 8, fr4 = qg * 4;
    int sAr = tid >> 3, sc8 = tid & 7;  // A-stage: 1 group/thread; B-stage: 4 rows, +32 apart

    // prologue: stage kt=0
    *(ushort8*)&A_l[sAr * 72 + sc8 * 8] =
        *(const ushort8*)(h1 + (size_t)(R0 + sAr) * 512 + sc8 * 8);
#pragma unroll
    for (int i = 0; i < 4; ++i) {
        int ro = sAr + i * 32;
        *(ushort8*)&B_l[ro * 72 + sc8 * 8] =
            *(const ushort8*)(w1t + ro * 512 + sc8 * 8);
    }
    __syncthreads();

    f32x4 acc[2][2];
#pragma unroll
    for (int a = 0; a < 2; ++a)
#pragma unroll
        for (int c = 0; c < 2; ++c) acc[a][c] = {0.f, 0.f, 0.f, 0.f};

#pragma unroll 1
    for (int kt = 0; kt < 8; ++kt) {
        // prefetch next K-tile into named registers (issued before MFMAs)
        ushort8 sa, sb0, sb1, sb2, sb3;
        if (kt < 7) {
            int koff = (kt + 1) * 64 + sc8 * 8;
            sa  = *(const ushort8*)(h1 + (size_t)(R0 + sAr) * 512 + koff);
            sb0 = *(const ushort8*)(w1t + (sAr +  0) * 512 + koff);
            sb1 = *(const ushort8*)(w1t + (sAr + 32) * 512 + koff);
            sb2 = *(const ushort8*)(w1t + (sAr + 64) * 512 + koff);
            sb3 = *(const ushort8*)(w1t + (sAr + 96) * 512 + koff);
        }
        // MFMA over current tile
#pragma unroll
        for (int kk = 0; kk < 2; ++kk) {
            short8 af[2], bf[2];
#pragma unroll
            for (int tr = 0; tr < 2; ++tr)
                af[tr] = *(const short8*)&A_l[(tr * 16 + frow) * 72 + kk * 32 + fk8];
#pragma unroll
            for (int tc = 0; tc < 2; ++tc)
                bf[tc] = *(const short8*)&B_l[(wave * 32 + tc * 16 + frow) * 72 + kk * 32 + fk8];
#pragma unroll
            for (int tr = 0; tr < 2; ++tr)
#pragma unroll
                for (int tc = 0; tc < 2; ++tc)
                    acc[tr][tc] = __builtin_amdgcn_mfma_f32_16x16x32_bf16(
                        af[tr], bf[tc], acc[tr][tc], 0, 0, 0);
        }
        __syncthreads();   // all waves done reading this K-tile
        if (kt < 7) {
            *(ushort8*)&A_l[sAr * 72 + sc8 * 8] = sa;
            *(ushort8*)&B_l[(sAr +  0) * 72 + sc8 * 8] = sb0;
            *(ushort8*)&B_l[(sAr + 32) * 72 + sc8 * 8] = sb1;
            *(ushort8*)&B_l[(sAr + 64) * 72 + sc8 * 8] = sb2;
            *(ushort8*)&B_l[(sAr + 96) * 72 + sc8 * 8] = sb3;
            __syncthreads();   // next K-tile visible
        }
    }

    // ---- epilogue: +b1, per-wave LN partials, cross-wave combine, stores ----
    float b1v[2], gv[2], bv[2];
#pragma unroll
    for (int tc = 0; tc < 2; ++tc) {
        int o = wave * 32 + tc * 16 + frow;
        b1v[tc] = b1[o]; gv[tc] = g[o]; bv[tc] = bb[o];
    }
#pragma unroll
    for (int tr = 0; tr < 2; ++tr)
#pragma unroll
        for (int r = 0; r < 4; ++r) {
            float s = 0.f, qq = 0.f;
#pragma unroll
            for (int tc = 0; tc < 2; ++tc) {
                float v = acc[tr][tc][r] + b1v[tc];
                acc[tr][tc][r] = v;
                s += v; qq += v * v;
            }
            s += __shfl_xor(s, 1); qq += __shfl_xor(qq, 1);
            s += __shfl_xor(s, 2); qq += __shfl_xor(qq, 2);
            s += __shfl_xor(s, 4); qq += __shfl_xor(qq, 4);
            s += __shfl_xor(s, 8); qq += __shfl_xor(qq, 8);
            if (frow == 0) {
                int row = tr * 16 + fr4 + r;
                ps_s[wave * 32 + row] = s;
                pq_s[wave * 32 + row] = qq;
            }
        }
    __syncthreads();
#pragma unroll
    for (int tr = 0; tr < 2; ++tr)
#pragma unroll
        for (int r = 0; r < 4; ++r) {
            int row = tr * 16 + fr4 + r;
            float S = ps_s[row] + ps_s[32 + row] + ps_s[64 + row] + ps_s[96 + row];
            float Q = pq_s[row] + pq_s[32 + row] + pq_s[64 + row] + pq_s[96 + row];
            float mu = S * (1.0f / 128.0f);
            float var = Q * (1.0f / 128.0f) - mu * mu;
            float rs = rsqrtf(fmaxf(var, 0.f) + LN_EPS);
            float* orow = &out[(size_t)(R0 + row) * 128 + wave * 32];
            orow[frow]      = (acc[tr][0][r] - mu) * rs * gv[0] + bv[0];
            orow[16 + frow] = (acc[tr][1][r] - mu) * rs * gv[1] + bv[1];
        }
}

extern "C" void kernel_launch(void* const* d_in, const int* in_sizes, int n_in,
                              void* d_out, int out_size, void* d_ws, size_t ws_size,
                              hipStream_t stream) {
    (void)in_sizes; (void)n_in; (void)out_size;
    const float* x   = (const float*)d_in[0];
    const float* w1  = (const float*)d_in[1];
    const float* w2  = (const float*)d_in[2];
    const float* fw0 = (const float*)d_in[3];
    const float* fb0 = (const float*)d_in[4];
    const float* fw1 = (const float*)d_in[5];
    const float* fb1 = (const float*)d_in[6];
    const float* lng = (const float*)d_in[7];
    const float* lnb = (const float*)d_in[8];
    float* out = (float*)d_out;

    char* ws = (char*)d_ws;
    ushort* T2h = (ushort*)(ws);                          // 8 KB (old Tc slot)
    ushort* T2l = (ushort*)(ws + 8192);                   // 8 KB (old Ts slot)
    float*  IT  = (float*)(ws + 16384);                   // 16 KB
    ushort* Wph = (ushort*)(ws + 32768);                  // 2 MB
    ushort* Wpl = (ushort*)(ws + 32768 + 2097152);        // 2 MB
    ushort* w0t = (ushort*)(ws + 4227072);                // 128 KB
    ushort* w1t = (ushort*)(ws + 4358144);                // 128 KB
    float*  buf0 = (float*)(ws + 4489216);                // F/f (32 MiB, in-place mix)
    ushort* hy   = (ushort*)(ws + 38043648);              // 64 MiB
    ushort* hsum = (ushort*)(ws + 105152512);             // 64 MiB
    const size_t need_two = 172261376ull;
    int two = (ws_size >= need_two) ? 1 : 0;
    ushort* hbfs = hy;   // fallback single-buffer

    k_setup<<<1, 256, 0, stream>>>(T2h, T2l, IT);
    k_wcvt <<<256, 256, 0, stream>>>(fw0, fw1, w0t, w1t);

    // y-branch: DFT over n, mix with w1, inverse over n -> hy[b,m,n,o] bf16
    k_wpack<<<4096, 256, 0, stream>>>(w1, Wph, Wpl);
    k_fft  <<<2048, 256, 0, stream>>>(x, T2h, T2l, buf0, 0);
    k_mixm <<<1024, 256, 0, stream>>>(buf0, Wph, Wpl, buf0);
    if (two) k_icdft<<<2048, 1024, 0, stream>>>(buf0, IT, hy, out, hy, 0);
    else     k_icdft<<<2048, 1024, 0, stream>>>(buf0, IT, hy, out, hy, 1);

    // x-branch: DFT over m, mix with w2, inverse over m; fused h = hy + hx -> hsum
    k_wpack<<<4096, 256, 0, stream>>>(w2, Wph, Wpl);
    k_fft  <<<2048, 256, 0, stream>>>(x, T2h, T2l, buf0, 1);
    k_mixm <<<1024, 256, 0, stream>>>(buf0, Wph, Wpl, buf0);
    if (two) k_icdft<<<2048, 1024, 0, stream>>>(buf0, IT, hsum, out, hy, 2);
    else     k_icdft<<<2048, 1024, 0, stream>>>(buf0, IT, hbfs, out, hy, 3);

    // FFN as two GEMMs over 262144 rows, chunked so h1 fits a dead ws buffer.
    if (two) {
        // 4 chunks x 65536 rows; h1 chunk = 64 MiB = exactly the dead hy region.
        for (int c = 0; c < 4; ++c) {
            const size_t off = (size_t)c * 65536 * 128;
            k_ffn1<<<4096, 256, 0, stream>>>(hsum + off, w0t, fb0, hy);
            k_ffn2<<<2048, 256, 0, stream>>>(hy, w1t, fb1, lng, lnb, out + off);
        }
    } else {
        // 8 chunks x 32768 rows; h1 chunk = 32 MiB = exactly buf0 (dead).
        ushort* h1buf = (ushort*)buf0;
        for (int c = 0; c < 8; ++c) {
            const size_t off = (size_t)c * 32768 * 128;
            k_ffn1<<<2048, 256, 0, stream>>>(hbfs + off, w0t, fb0, h1buf);
            k_ffn2<<<1024, 256, 0, stream>>>(h1buf, w1t, fb1, lng, lnb, out + off);
        }
    }
}